// Round 21
// baseline (180.199 us; speedup 1.0000x reference)
//
#include <hip/hip_runtime.h>

typedef short short8 __attribute__((ext_vector_type(8)));
typedef short short4_ __attribute__((ext_vector_type(4)));
typedef float f32x4 __attribute__((ext_vector_type(4)));

#define GLD16(gsrc, ldst) \
  __builtin_amdgcn_global_load_lds((__attribute__((address_space(1))) const void*)(gsrc), \
                                   (__attribute__((address_space(3))) void*)(ldst), 16, 0, 0)

// Raw barrier: wait only for LDS ops (dbuf handoff); global stores stay in flight.
#define BAR() do { asm volatile("s_waitcnt lgkmcnt(0)" ::: "memory"); \
  __builtin_amdgcn_sched_barrier(0); __builtin_amdgcn_s_barrier(); } while (0)

static __device__ __forceinline__ short f2bf(float f) {
  union { float f; unsigned u; } x; x.f = f;
  unsigned r = x.u + 0x7fffu + ((x.u >> 16) & 1u);
  return (short)(r >> 16);
}
static __device__ __forceinline__ float bf2f(unsigned short h) {
  union { unsigned u; float f; } x; x.u = ((unsigned)h) << 16;
  return x.f;
}

// ------------- kernel 1: pack W (H,D,DK) f32 -> Bt (H*DK, D) bf16 -------------
__global__ __launch_bounds__(256) void pack_w(
    const float* __restrict__ wq, const float* __restrict__ wk, const float* __restrict__ wv,
    short* __restrict__ oq, short* __restrict__ ok, short* __restrict__ ov) {
  int z = blockIdx.z;
  const float* W = (z == 0) ? wq : (z == 1) ? wk : wv;
  short* o = ((z == 0) ? oq : (z == 1) ? ok : ov) + (size_t)blockIdx.x * 1024;
  int c = blockIdx.x;
  int h = c >> 6, kk = c & 63;
  const float* src = W + (size_t)h * 65536 + kk;  // + d*64
  #pragma unroll
  for (int it = 0; it < 4; ++it) {
    int d = it * 256 + threadIdx.x;
    o[d] = f2bf(src[(size_t)d * 64]);
  }
}

// ------------- kernel 2: projection GEMM, f32-A FUSED CAST (no cast kernel) -------------
// A read directly from f32 inputs, reg-staged + converted while staging (cast∘stage
// == stage∘cast: bit-identical numerics to the cast+GLD16 pipeline). B (bf16 packed
// weights) stays GLD16. Both double-buffered; next-chunk loads issued before compute.
__global__ __launch_bounds__(256) void proj_gemm(
    const float* __restrict__ qf, const float* __restrict__ kf, const float* __restrict__ vf,
    const short* __restrict__ wq, const short* __restrict__ wk, const short* __restrict__ wv,
    short* __restrict__ pq, short* __restrict__ pk, short* __restrict__ pv) {
  int z = blockIdx.z;
  const float* A  = (z == 0) ? qf : (z == 1) ? kf : vf;
  const short* Bt = (z == 0) ? wq : (z == 1) ? wk : wv;
  short* C        = (z == 0) ? pq : (z == 1) ? pk : pv;
  __shared__ __attribute__((aligned(16))) short As[2][128 * 32];
  __shared__ __attribute__((aligned(16))) short Bs[2][128 * 32];
  int t = threadIdx.x, l = t & 63, w = t >> 6;
  int wr = w >> 1, wc = w & 1;
  int lr = l & 15, lk = l >> 4;
  int bm0 = blockIdx.y * 128, bn0 = blockIdx.x * 128;
  const f32x4 Z = {0.f, 0.f, 0.f, 0.f};
  f32x4 acc[4][4];
  #pragma unroll
  for (int m = 0; m < 4; ++m)
    #pragma unroll
    for (int n = 0; n < 4; ++n) acc[m][n] = Z;

  // A staging (f32 source): thread t covers row sr = t>>1, k-half sh = t&1 (16 floats)
  int sr = t >> 1, sh = t & 1;
  const float* ga = A + (size_t)(bm0 + sr) * 1024 + sh * 16;
  int aoff = sr * 32 + sh * 16;
  // B staging (GLD16, validated geometry)
  int boff0 = w * 2 * 1024 + l * 16;
  int row0 = boff0 >> 6, ke0 = (boff0 & 63) >> 1;
  int boff1 = boff0 + 1024;
  int row1 = boff1 >> 6, ke1 = (boff1 & 63) >> 1;
  const short* gb0 = Bt + (size_t)(bn0 + row0) * 1024 + ke0;
  const short* gb1 = Bt + (size_t)(bn0 + row1) * 1024 + ke1;
  int lo = (w * 2) * 512, lo1 = (w * 2 + 1) * 512;

  float4 f0, f1, f2, f3;
  // prologue: stage chunk 0 -> buf 0
  f0 = *(const float4*)(ga + 0); f1 = *(const float4*)(ga + 4);
  f2 = *(const float4*)(ga + 8); f3 = *(const float4*)(ga + 12);
  {
    short8 alo, ahi;
    alo[0] = f2bf(f0.x); alo[1] = f2bf(f0.y); alo[2] = f2bf(f0.z); alo[3] = f2bf(f0.w);
    alo[4] = f2bf(f1.x); alo[5] = f2bf(f1.y); alo[6] = f2bf(f1.z); alo[7] = f2bf(f1.w);
    ahi[0] = f2bf(f2.x); ahi[1] = f2bf(f2.y); ahi[2] = f2bf(f2.z); ahi[3] = f2bf(f2.w);
    ahi[4] = f2bf(f3.x); ahi[5] = f2bf(f3.y); ahi[6] = f2bf(f3.z); ahi[7] = f2bf(f3.w);
    *(short8*)(As[0] + aoff) = alo;
    *(short8*)(As[0] + aoff + 8) = ahi;
  }
  GLD16(gb0, Bs[0] + lo);
  GLD16(gb1, Bs[0] + lo1);
  __syncthreads();

  for (int kb = 0; kb < 1024; kb += 32) {
    int cur = (kb >> 5) & 1;
    if (kb < 992) {  // issue next chunk's A loads (to regs) and B GLD16 before compute
      int kn = kb + 32;
      f0 = *(const float4*)(ga + kn); f1 = *(const float4*)(ga + kn + 4);
      f2 = *(const float4*)(ga + kn + 8); f3 = *(const float4*)(ga + kn + 12);
      GLD16(gb0 + kn, Bs[cur ^ 1] + lo);
      GLD16(gb1 + kn, Bs[cur ^ 1] + lo1);
    }
    short8 a[4], bfr[4];
    #pragma unroll
    for (int m = 0; m < 4; ++m)
      a[m] = *(const short8*)(As[cur] + (wr * 64 + m * 16 + lr) * 32 + lk * 8);
    #pragma unroll
    for (int n = 0; n < 4; ++n)
      bfr[n] = *(const short8*)(Bs[cur] + (wc * 64 + n * 16 + lr) * 32 + lk * 8);
    __builtin_amdgcn_s_setprio(1);
    #pragma unroll
    for (int m = 0; m < 4; ++m)
      #pragma unroll
      for (int n = 0; n < 4; ++n)
        acc[m][n] = __builtin_amdgcn_mfma_f32_16x16x32_bf16(a[m], bfr[n], acc[m][n], 0, 0, 0);
    __builtin_amdgcn_s_setprio(0);
    if (kb < 992) {  // convert + write next A chunk to the other buffer
      short8 alo, ahi;
      alo[0] = f2bf(f0.x); alo[1] = f2bf(f0.y); alo[2] = f2bf(f0.z); alo[3] = f2bf(f0.w);
      alo[4] = f2bf(f1.x); alo[5] = f2bf(f1.y); alo[6] = f2bf(f1.z); alo[7] = f2bf(f1.w);
      ahi[0] = f2bf(f2.x); ahi[1] = f2bf(f2.y); ahi[2] = f2bf(f2.z); ahi[3] = f2bf(f2.w);
      ahi[4] = f2bf(f3.x); ahi[5] = f2bf(f3.y); ahi[6] = f2bf(f3.z); ahi[7] = f2bf(f3.w);
      *(short8*)(As[cur ^ 1] + aoff) = alo;
      *(short8*)(As[cur ^ 1] + aoff + 8) = ahi;
    }
    __syncthreads();
  }
  #pragma unroll
  for (int m = 0; m < 4; ++m)
    #pragma unroll
    for (int n = 0; n < 4; ++n)
      #pragma unroll
      for (int i = 0; i < 4; ++i) {
        int r = bm0 + wr * 64 + m * 16 + lk * 4 + i;
        int cc = bn0 + wc * 64 + n * 16 + lr;
        C[(size_t)r * 1024 + cc] = f2bf(acc[m][n][i]);
      }
}

// ------------- kernel 3: V transpose  pv[b*N+n][h*64+dv] -> vt[hb][dv][n] -------------
__global__ __launch_bounds__(256) void vtrans(
    const short* __restrict__ pv, short* __restrict__ vt) {
  __shared__ short T[64 * 72];
  int t = threadIdx.x;
  int hb = blockIdx.y, h = hb >> 2, b = hb & 3;
  int n0 = blockIdx.x * 64;
  const short* src = pv + (size_t)b * 1048576 + (size_t)n0 * 1024 + h * 64;
  #pragma unroll
  for (int it = 0; it < 2; ++it) {
    int id = it * 256 + t;
    int row = id >> 3, seg = id & 7;
    *(short8*)(T + row * 72 + seg * 8) = *(const short8*)(src + (size_t)row * 1024 + seg * 8);
  }
  __syncthreads();
  short* dst = vt + (size_t)hb * 65536 + n0;
  #pragma unroll
  for (int it = 0; it < 2; ++it) {
    int id = it * 256 + t;
    int dv = id >> 3, seg = id & 7;
    short8 vv;
    #pragma unroll
    for (int jj = 0; jj < 8; ++jj) vv[jj] = T[(seg * 8 + jj) * 72 + dv];
    *(short8*)(dst + (size_t)dv * 1024 + seg * 8) = vv;
  }
}

// ------------- kernel 4: fused attention, SWAPPED QK^T (exact R17, best: 155.8) -------------
__global__ __launch_bounds__(512) void attn_fused(
    const short* __restrict__ pq, const short* __restrict__ pk, const short* __restrict__ vt,
    float* __restrict__ dout) {
  __shared__ __attribute__((aligned(16))) short Ks[2][64 * 64];
  __shared__ __attribute__((aligned(16))) short Vs[2][64 * 64];
  __shared__ __attribute__((aligned(16))) short Ps[128 * 64];
  int t = threadIdx.x, l = t & 63, w = t >> 6;
  int lr = l & 15, lk = l >> 4;
  int r7 = lr & 7;
  int bid = blockIdx.x;
  int swz = (bid & 7) * 64 + (bid >> 3);           // XCD c -> hb in [c*8, c*8+8)
  int hb = swz >> 3, qt = swz & 7;
  int h = hb >> 2, b = hb & 3;                     // hb = h*B + b
  int q0 = qt * 128;
  const short* Qg = pq + (size_t)b * 1048576 + h * 64;
  const short* Kg = pk + (size_t)b * 1048576 + h * 64;
  const short* Vt = vt + (size_t)hb * 65536;
  float* attnp = dout + 4194304 + (size_t)hb * 1048576;
  const f32x4 Z = {0.f, 0.f, 0.f, 0.f};
  const float scale = 0.125f;
  int r0 = w * 16;
  int sj = t >> 3, slt = t & 7;                    // staging: row sj, slot slt
  int stoff = sj * 64 + ((slt ^ (sj & 7)) << 3);   // swizzled staging addr (shorts)

  // Q fragments direct from global (one-time)
  const short* qrow = Qg + (size_t)(q0 + r0 + lr) * 1024;
  short8 aq[2];
  aq[0] = *(const short8*)(qrow + lk * 8);
  aq[1] = *(const short8*)(qrow + 32 + lk * 8);

  short8 ka, va;
  // prologue: stage K chunk 0 -> buf 0
  ka = *(const short8*)(Kg + (size_t)sj * 1024 + slt * 8);
  *(short8*)(Ks[0] + stoff) = ka;
  BAR();

  float s = 0.0f;

  // ---- pass 1: sum of exp(scores); swapped mfma(K, Q) ----
  for (int nc = 0; nc < 16; ++nc) {
    int cur = nc & 1;
    if (nc < 15)
      ka = *(const short8*)(Kg + (size_t)((nc + 1) * 64 + sj) * 1024 + slt * 8);
    f32x4 acc[4] = {Z, Z, Z, Z};
    __builtin_amdgcn_s_setprio(1);
    #pragma unroll
    for (int kk = 0; kk < 2; ++kk)
      #pragma unroll
      for (int n = 0; n < 4; ++n) {
        short8 bk = *(const short8*)(Ks[cur] + (n * 16 + lr) * 64 + (((kk * 4 + lk) ^ r7) << 3));
        acc[n] = __builtin_amdgcn_mfma_f32_16x16x32_bf16(bk, aq[kk], acc[n], 0, 0, 0);
      }
    __builtin_amdgcn_s_setprio(0);
    #pragma unroll
    for (int n = 0; n < 4; ++n)
      s += __expf(acc[n][0] * scale) + __expf(acc[n][1] * scale) +
           __expf(acc[n][2] * scale) + __expf(acc[n][3] * scale);
    if (nc < 15)
      *(short8*)(Ks[cur ^ 1] + stoff) = ka;
    BAR();
  }
  // reduce across the 4 lk-groups sharing each q-row
  s += __shfl_xor(s, 16, 64);
  s += __shfl_xor(s, 32, 64);
  float inv = 1.0f / s;

  // re-prime buf 0 with chunk 0 (K and V)
  ka = *(const short8*)(Kg + (size_t)sj * 1024 + slt * 8);
  va = *(const short8*)(Vt + (size_t)sj * 1024 + slt * 8);
  *(short8*)(Ks[0] + stoff) = ka;
  *(short8*)(Vs[0] + stoff) = va;
  BAR();

  // ---- pass 2: swapped QK -> exp (lane-local) -> attn store from regs + Ps b64 -> PV ----
  f32x4 acco[4] = {Z, Z, Z, Z};
  float* arow = attnp + (size_t)(q0 + r0 + lr) * 1024 + lk * 4;
  short* psrow = Ps + (r0 + lr) * 64;
  int wsw = (lr & 7) << 1;                         // 8B-granular XOR key
  for (int nc = 0; nc < 16; ++nc) {
    int cur = nc & 1;
    if (nc < 15) {
      ka = *(const short8*)(Kg + (size_t)((nc + 1) * 64 + sj) * 1024 + slt * 8);
      va = *(const short8*)(Vt + (size_t)sj * 1024 + (nc + 1) * 64 + slt * 8);
    }
    f32x4 acc[4] = {Z, Z, Z, Z};
    __builtin_amdgcn_s_setprio(1);
    #pragma unroll
    for (int kk = 0; kk < 2; ++kk)
      #pragma unroll
      for (int n = 0; n < 4; ++n) {
        short8 bk = *(const short8*)(Ks[cur] + (n * 16 + lr) * 64 + (((kk * 4 + lk) ^ r7) << 3));
        acc[n] = __builtin_amdgcn_mfma_f32_16x16x32_bf16(bk, aq[kk], acc[n], 0, 0, 0);
      }
    __builtin_amdgcn_s_setprio(0);
    // normalized P: attn f32 direct from regs; bf16 4-pack -> Ps (b64, swizzled)
    #pragma unroll
    for (int n = 0; n < 4; ++n) {
      float e0 = __expf(acc[n][0] * scale) * inv;
      float e1 = __expf(acc[n][1] * scale) * inv;
      float e2 = __expf(acc[n][2] * scale) * inv;
      float e3 = __expf(acc[n][3] * scale) * inv;
      float4 fo = {e0, e1, e2, e3};
      *(float4*)(arow + nc * 64 + n * 16) = fo;    // col = nc*64 + 16n + 4lk + i
      short4_ p4;
      p4[0] = f2bf(e0); p4[1] = f2bf(e1); p4[2] = f2bf(e2); p4[3] = f2bf(e3);
      *(short4_*)(psrow + (((n * 4 + lk) ^ wsw) << 2)) = p4;
    }
    // PV: ap from Ps (b128, swizzled read matches b64 writes), bv from LDS V
    #pragma unroll
    for (int kk = 0; kk < 2; ++kk) {
      short8 ap = *(const short8*)(psrow + (((kk * 4 + lk) ^ r7) << 3));
      __builtin_amdgcn_s_setprio(1);
      #pragma unroll
      for (int f = 0; f < 4; ++f) {
        short8 bv = *(const short8*)(Vs[cur] + (f * 16 + lr) * 64 + (((kk * 4 + lk) ^ r7) << 3));
        acco[f] = __builtin_amdgcn_mfma_f32_16x16x32_bf16(ap, bv, acco[f], 0, 0, 0);
      }
      __builtin_amdgcn_s_setprio(0);
    }
    if (nc < 15) {
      *(short8*)(Ks[cur ^ 1] + stoff) = ka;
      *(short8*)(Vs[cur ^ 1] + stoff) = va;
    }
    BAR();
  }
  // out[b][n][h*64+dv] (f32); PV C-layout unchanged (col=dv, row=q)
  #pragma unroll
  for (int f = 0; f < 4; ++f)
    #pragma unroll
    for (int i = 0; i < 4; ++i) {
      int row = q0 + r0 + lk * 4 + i;
      int dv = f * 16 + lr;
      dout[(size_t)b * 1048576 + (size_t)row * 1024 + h * 64 + dv] = acco[f][i];
    }
}

extern "C" void kernel_launch(void* const* d_in, const int* in_sizes, int n_in,
                              void* d_out, int out_size, void* d_ws, size_t ws_size,
                              hipStream_t stream) {
  const void* big[3] = {0, 0, 0};
  const void* small[3] = {0, 0, 0};
  int nb = 0, ns = 0;
  for (int i = 0; i < n_in && i < 6; ++i) {
    if (in_sizes[i] == 4194304) { if (nb < 3) big[nb++] = d_in[i]; }
    else                        { if (ns < 3) small[ns++] = d_in[i]; }
  }
  const float *q, *k, *v, *wq, *wk, *wv;
  if (nb == 3 && ns == 3) {
    q = (const float*)big[0]; k = (const float*)big[1]; v = (const float*)big[2];
    wq = (const float*)small[0]; wk = (const float*)small[1]; wv = (const float*)small[2];
  } else {
    q = (const float*)d_in[0]; k = (const float*)d_in[1]; v = (const float*)d_in[2];
    wq = (const float*)d_in[3]; wk = (const float*)d_in[4]; wv = (const float*)d_in[5];
  }
  // workspace layout (shorts): same validated 65 MB footprint (xq/xk/xv slots unused now)
  short* W   = (short*)d_ws;
  short* wtq = W + 12582912;
  short* wtk = W + 13631488;
  short* wtv = W + 14680064;
  short* pq  = W + 15728640;
  short* pk  = W + 19922944;
  short* pv  = W + 24117248;
  short* vt  = W + 28311552;
  float* out = (float*)d_out;

  pack_w<<<dim3(1024, 1, 3), 256, 0, stream>>>(wq, wk, wv, wtq, wtk, wtv);
  proj_gemm<<<dim3(8, 32, 3), 256, 0, stream>>>(q, k, v, wtq, wtk, wtv, pq, pk, pv);
  vtrans<<<dim3(16, 64), 256, 0, stream>>>(pv, vt);
  attn_fused<<<dim3(512), 512, 0, stream>>>(pq, pk, vt, out);
}

// Round 22
// 163.299 us; speedup vs baseline: 1.1035x; 1.1035x over previous
//
#include <hip/hip_runtime.h>

typedef short short8 __attribute__((ext_vector_type(8)));
typedef short short4_ __attribute__((ext_vector_type(4)));
typedef float f32x4 __attribute__((ext_vector_type(4)));

#define GLD16(gsrc, ldst) \
  __builtin_amdgcn_global_load_lds((__attribute__((address_space(1))) const void*)(gsrc), \
                                   (__attribute__((address_space(3))) void*)(ldst), 16, 0, 0)

// Raw barrier: wait only for LDS ops (dbuf handoff); global stores stay in flight.
#define BAR() do { asm volatile("s_waitcnt lgkmcnt(0)" ::: "memory"); \
  __builtin_amdgcn_sched_barrier(0); __builtin_amdgcn_s_barrier(); } while (0)

static __device__ __forceinline__ short f2bf(float f) {
  union { float f; unsigned u; } x; x.f = f;
  unsigned r = x.u + 0x7fffu + ((x.u >> 16) & 1u);
  return (short)(r >> 16);
}
static __device__ __forceinline__ float bf2f(unsigned short h) {
  union { unsigned u; float f; } x; x.u = ((unsigned)h) << 16;
  return x.f;
}

// ---------------- kernel 1: cast q,k,v f32 -> bf16  AND pack weights (merged) ----------------
__global__ __launch_bounds__(256) void cast_pack(
    const float* __restrict__ q, const float* __restrict__ k, const float* __restrict__ v,
    const float* __restrict__ wq, const float* __restrict__ wk, const float* __restrict__ wv,
    short* __restrict__ xq, short* __restrict__ xk, short* __restrict__ xv,
    short* __restrict__ oq, short* __restrict__ ok, short* __restrict__ ov) {
  int z = blockIdx.z;
  if (blockIdx.x < 4096) {             // cast q/k/v
    const float* s = (z == 0) ? q : (z == 1) ? k : v;
    short* d = (z == 0) ? xq : (z == 1) ? xk : xv;
    int i = (blockIdx.x * 256 + threadIdx.x) * 4;
    float4 f = *(const float4*)(s + i);
    short4_ o;
    o[0] = f2bf(f.x); o[1] = f2bf(f.y); o[2] = f2bf(f.z); o[3] = f2bf(f.w);
    *(short4_*)(d + i) = o;
  } else {                             // pack W (H,D,DK) -> Bt (H*DK, D)
    const float* W = (z == 0) ? wq : (z == 1) ? wk : wv;
    int c = blockIdx.x - 4096;
    short* o = ((z == 0) ? oq : (z == 1) ? ok : ov) + (size_t)c * 1024;
    int h = c >> 6, kk = c & 63;
    const float* src = W + (size_t)h * 65536 + kk;  // + d*64
    #pragma unroll
    for (int it = 0; it < 4; ++it) {
      int d = it * 256 + threadIdx.x;
      o[d] = f2bf(src[(size_t)d * 64]);
    }
  }
}

// ------------- kernel 2: projection GEMM, BK=64 as two half-tiles (R16/R17, validated) -------------
__global__ __launch_bounds__(256) void proj_gemm(
    const short* __restrict__ xq, const short* __restrict__ xk, const short* __restrict__ xv,
    const short* __restrict__ wq, const short* __restrict__ wk, const short* __restrict__ wv,
    short* __restrict__ pq, short* __restrict__ pk, short* __restrict__ pv) {
  int z = blockIdx.z;
  const short* A  = (z == 0) ? xq : (z == 1) ? xk : xv;
  const short* Bt = (z == 0) ? wq : (z == 1) ? wk : wv;
  short* C        = (z == 0) ? pq : (z == 1) ? pk : pv;
  __shared__ __attribute__((aligned(16))) short As[2][128 * 32];
  __shared__ __attribute__((aligned(16))) short Bs[2][128 * 32];
  int t = threadIdx.x, l = t & 63, w = t >> 6;
  int wr = w >> 1, wc = w & 1;
  int lr = l & 15, lk = l >> 4;
  int bm0 = blockIdx.y * 128, bn0 = blockIdx.x * 128;
  const f32x4 Z = {0.f, 0.f, 0.f, 0.f};
  f32x4 acc[4][4];
  #pragma unroll
  for (int m = 0; m < 4; ++m)
    #pragma unroll
    for (int n = 0; n < 4; ++n) acc[m][n] = Z;

  int boff0 = w * 2 * 1024 + l * 16;
  int row0 = boff0 >> 6, ke0 = (boff0 & 63) >> 1;
  int boff1 = boff0 + 1024;
  int row1 = boff1 >> 6, ke1 = (boff1 & 63) >> 1;
  const short* ga0 = A + (size_t)(bm0 + row0) * 1024 + ke0;
  const short* ga1 = A + (size_t)(bm0 + row1) * 1024 + ke1;
  const short* gb0 = Bt + (size_t)(bn0 + row0) * 1024 + ke0;
  const short* gb1 = Bt + (size_t)(bn0 + row1) * 1024 + ke1;
  int lo = (w * 2) * 512, lo1 = (w * 2 + 1) * 512;

  for (int kb = 0; kb < 1024; kb += 64) {
    #pragma unroll
    for (int hh = 0; hh < 2; ++hh) {
      int kc = kb + hh * 32;
      GLD16(ga0 + kc, As[hh] + lo);
      GLD16(ga1 + kc, As[hh] + lo1);
      GLD16(gb0 + kc, Bs[hh] + lo);
      GLD16(gb1 + kc, Bs[hh] + lo1);
    }
    __syncthreads();
    #pragma unroll
    for (int hh = 0; hh < 2; ++hh) {
      short8 a[4], bfr[4];
      #pragma unroll
      for (int m = 0; m < 4; ++m)
        a[m] = *(const short8*)(As[hh] + (wr * 64 + m * 16 + lr) * 32 + lk * 8);
      #pragma unroll
      for (int n = 0; n < 4; ++n)
        bfr[n] = *(const short8*)(Bs[hh] + (wc * 64 + n * 16 + lr) * 32 + lk * 8);
      __builtin_amdgcn_s_setprio(1);
      #pragma unroll
      for (int m = 0; m < 4; ++m)
        #pragma unroll
        for (int n = 0; n < 4; ++n)
          acc[m][n] = __builtin_amdgcn_mfma_f32_16x16x32_bf16(a[m], bfr[n], acc[m][n], 0, 0, 0);
      __builtin_amdgcn_s_setprio(0);
    }
    __syncthreads();
  }
  #pragma unroll
  for (int m = 0; m < 4; ++m)
    #pragma unroll
    for (int n = 0; n < 4; ++n)
      #pragma unroll
      for (int i = 0; i < 4; ++i) {
        int r = bm0 + wr * 64 + m * 16 + lk * 4 + i;
        int cc = bn0 + wc * 64 + n * 16 + lr;
        C[(size_t)r * 1024 + cc] = f2bf(acc[m][n][i]);
      }
}

// ------------- kernel 3: V transpose  pv[b*N+n][h*64+dv] -> vt[hb][dv][n] -------------
__global__ __launch_bounds__(256) void vtrans(
    const short* __restrict__ pv, short* __restrict__ vt) {
  __shared__ short T[64 * 72];
  int t = threadIdx.x;
  int hb = blockIdx.y, h = hb >> 2, b = hb & 3;
  int n0 = blockIdx.x * 64;
  const short* src = pv + (size_t)b * 1048576 + (size_t)n0 * 1024 + h * 64;
  #pragma unroll
  for (int it = 0; it < 2; ++it) {
    int id = it * 256 + t;
    int row = id >> 3, seg = id & 7;
    *(short8*)(T + row * 72 + seg * 8) = *(const short8*)(src + (size_t)row * 1024 + seg * 8);
  }
  __syncthreads();
  short* dst = vt + (size_t)hb * 65536 + n0;
  #pragma unroll
  for (int it = 0; it < 2; ++it) {
    int id = it * 256 + t;
    int dv = id >> 3, seg = id & 7;
    short8 vv;
    #pragma unroll
    for (int jj = 0; jj < 8; ++jj) vv[jj] = T[(seg * 8 + jj) * 72 + dv];
    *(short8*)(dst + (size_t)dv * 1024 + seg * 8) = vv;
  }
}

// ------------- kernel 4: fused attention, SWAPPED QK^T (R17 = best 155.8) -------------
// Only change vs R17: softmax exp in log2-space (exp2f(acc*SC2)) — drops the
// per-exp v_mul that __expf's lowering carries. Same transcendental count.
#define SC2 0.18033688011112042f   // 0.125 * log2(e)
__global__ __launch_bounds__(512) void attn_fused(
    const short* __restrict__ pq, const short* __restrict__ pk, const short* __restrict__ vt,
    float* __restrict__ dout) {
  __shared__ __attribute__((aligned(16))) short Ks[2][64 * 64];
  __shared__ __attribute__((aligned(16))) short Vs[2][64 * 64];
  __shared__ __attribute__((aligned(16))) short Ps[128 * 64];
  int t = threadIdx.x, l = t & 63, w = t >> 6;
  int lr = l & 15, lk = l >> 4;
  int r7 = lr & 7;
  int bid = blockIdx.x;
  int swz = (bid & 7) * 64 + (bid >> 3);           // XCD c -> hb in [c*8, c*8+8)
  int hb = swz >> 3, qt = swz & 7;
  int h = hb >> 2, b = hb & 3;                     // hb = h*B + b
  int q0 = qt * 128;
  const short* Qg = pq + (size_t)b * 1048576 + h * 64;
  const short* Kg = pk + (size_t)b * 1048576 + h * 64;
  const short* Vt = vt + (size_t)hb * 65536;
  float* attnp = dout + 4194304 + (size_t)hb * 1048576;
  const f32x4 Z = {0.f, 0.f, 0.f, 0.f};
  int r0 = w * 16;
  int sj = t >> 3, slt = t & 7;                    // staging: row sj, slot slt
  int stoff = sj * 64 + ((slt ^ (sj & 7)) << 3);   // swizzled staging addr (shorts)

  // Q fragments direct from global (one-time)
  const short* qrow = Qg + (size_t)(q0 + r0 + lr) * 1024;
  short8 aq[2];
  aq[0] = *(const short8*)(qrow + lk * 8);
  aq[1] = *(const short8*)(qrow + 32 + lk * 8);

  short8 ka, va;
  // prologue: stage K chunk 0 -> buf 0
  ka = *(const short8*)(Kg + (size_t)sj * 1024 + slt * 8);
  *(short8*)(Ks[0] + stoff) = ka;
  BAR();

  float s = 0.0f;

  // ---- pass 1: sum of exp(scores); swapped mfma(K, Q) ----
  for (int nc = 0; nc < 16; ++nc) {
    int cur = nc & 1;
    if (nc < 15)
      ka = *(const short8*)(Kg + (size_t)((nc + 1) * 64 + sj) * 1024 + slt * 8);
    f32x4 acc[4] = {Z, Z, Z, Z};
    __builtin_amdgcn_s_setprio(1);
    #pragma unroll
    for (int kk = 0; kk < 2; ++kk)
      #pragma unroll
      for (int n = 0; n < 4; ++n) {
        short8 bk = *(const short8*)(Ks[cur] + (n * 16 + lr) * 64 + (((kk * 4 + lk) ^ r7) << 3));
        acc[n] = __builtin_amdgcn_mfma_f32_16x16x32_bf16(bk, aq[kk], acc[n], 0, 0, 0);
      }
    __builtin_amdgcn_s_setprio(0);
    #pragma unroll
    for (int n = 0; n < 4; ++n)
      s += exp2f(acc[n][0] * SC2) + exp2f(acc[n][1] * SC2) +
           exp2f(acc[n][2] * SC2) + exp2f(acc[n][3] * SC2);
    if (nc < 15)
      *(short8*)(Ks[cur ^ 1] + stoff) = ka;
    BAR();
  }
  // reduce across the 4 lk-groups sharing each q-row
  s += __shfl_xor(s, 16, 64);
  s += __shfl_xor(s, 32, 64);
  float inv = 1.0f / s;

  // re-prime buf 0 with chunk 0 (K and V)
  ka = *(const short8*)(Kg + (size_t)sj * 1024 + slt * 8);
  va = *(const short8*)(Vt + (size_t)sj * 1024 + slt * 8);
  *(short8*)(Ks[0] + stoff) = ka;
  *(short8*)(Vs[0] + stoff) = va;
  BAR();

  // ---- pass 2: swapped QK -> exp (lane-local) -> attn store from regs + Ps b64 -> PV ----
  f32x4 acco[4] = {Z, Z, Z, Z};
  float* arow = attnp + (size_t)(q0 + r0 + lr) * 1024 + lk * 4;
  short* psrow = Ps + (r0 + lr) * 64;
  int wsw = (lr & 7) << 1;                         // 8B-granular XOR key
  for (int nc = 0; nc < 16; ++nc) {
    int cur = nc & 1;
    if (nc < 15) {
      ka = *(const short8*)(Kg + (size_t)((nc + 1) * 64 + sj) * 1024 + slt * 8);
      va = *(const short8*)(Vt + (size_t)sj * 1024 + (nc + 1) * 64 + slt * 8);
    }
    f32x4 acc[4] = {Z, Z, Z, Z};
    __builtin_amdgcn_s_setprio(1);
    #pragma unroll
    for (int kk = 0; kk < 2; ++kk)
      #pragma unroll
      for (int n = 0; n < 4; ++n) {
        short8 bk = *(const short8*)(Ks[cur] + (n * 16 + lr) * 64 + (((kk * 4 + lk) ^ r7) << 3));
        acc[n] = __builtin_amdgcn_mfma_f32_16x16x32_bf16(bk, aq[kk], acc[n], 0, 0, 0);
      }
    __builtin_amdgcn_s_setprio(0);
    // normalized P: attn f32 direct from regs; bf16 4-pack -> Ps (b64, swizzled)
    #pragma unroll
    for (int n = 0; n < 4; ++n) {
      float e0 = exp2f(acc[n][0] * SC2) * inv;
      float e1 = exp2f(acc[n][1] * SC2) * inv;
      float e2 = exp2f(acc[n][2] * SC2) * inv;
      float e3 = exp2f(acc[n][3] * SC2) * inv;
      float4 fo = {e0, e1, e2, e3};
      *(float4*)(arow + nc * 64 + n * 16) = fo;    // col = nc*64 + 16n + 4lk + i
      short4_ p4;
      p4[0] = f2bf(e0); p4[1] = f2bf(e1); p4[2] = f2bf(e2); p4[3] = f2bf(e3);
      *(short4_*)(psrow + (((n * 4 + lk) ^ wsw) << 2)) = p4;
    }
    // PV: ap from Ps (b128, swizzled read matches b64 writes), bv from LDS V
    #pragma unroll
    for (int kk = 0; kk < 2; ++kk) {
      short8 ap = *(const short8*)(psrow + (((kk * 4 + lk) ^ r7) << 3));
      __builtin_amdgcn_s_setprio(1);
      #pragma unroll
      for (int f = 0; f < 4; ++f) {
        short8 bv = *(const short8*)(Vs[cur] + (f * 16 + lr) * 64 + (((kk * 4 + lk) ^ r7) << 3));
        acco[f] = __builtin_amdgcn_mfma_f32_16x16x32_bf16(ap, bv, acco[f], 0, 0, 0);
      }
      __builtin_amdgcn_s_setprio(0);
    }
    if (nc < 15) {
      *(short8*)(Ks[cur ^ 1] + stoff) = ka;
      *(short8*)(Vs[cur ^ 1] + stoff) = va;
    }
    BAR();
  }
  // out[b][n][h*64+dv] (f32); PV C-layout unchanged (col=dv, row=q)
  #pragma unroll
  for (int f = 0; f < 4; ++f)
    #pragma unroll
    for (int i = 0; i < 4; ++i) {
      int row = q0 + r0 + lk * 4 + i;
      int dv = f * 16 + lr;
      dout[(size_t)b * 1048576 + (size_t)row * 1024 + h * 64 + dv] = acco[f][i];
    }
}

extern "C" void kernel_launch(void* const* d_in, const int* in_sizes, int n_in,
                              void* d_out, int out_size, void* d_ws, size_t ws_size,
                              hipStream_t stream) {
  const void* big[3] = {0, 0, 0};
  const void* small[3] = {0, 0, 0};
  int nb = 0, ns = 0;
  for (int i = 0; i < n_in && i < 6; ++i) {
    if (in_sizes[i] == 4194304) { if (nb < 3) big[nb++] = d_in[i]; }
    else                        { if (ns < 3) small[ns++] = d_in[i]; }
  }
  const float *q, *k, *v, *wq, *wk, *wv;
  if (nb == 3 && ns == 3) {
    q = (const float*)big[0]; k = (const float*)big[1]; v = (const float*)big[2];
    wq = (const float*)small[0]; wk = (const float*)small[1]; wv = (const float*)small[2];
  } else {
    q = (const float*)d_in[0]; k = (const float*)d_in[1]; v = (const float*)d_in[2];
    wq = (const float*)d_in[3]; wk = (const float*)d_in[4]; wv = (const float*)d_in[5];
  }
  // workspace layout (shorts): total 32,505,856 shorts = 65 MB (validated size)
  short* W   = (short*)d_ws;
  short* xq  = W;
  short* xk  = W + 4194304;
  short* xv  = W + 8388608;
  short* wtq = W + 12582912;
  short* wtk = W + 13631488;
  short* wtv = W + 14680064;
  short* pq  = W + 15728640;
  short* pk  = W + 19922944;
  short* pv  = W + 24117248;
  short* vt  = W + 28311552;
  float* out = (float*)d_out;

  cast_pack<<<dim3(5120, 1, 3), 256, 0, stream>>>(q, k, v, wq, wk, wv,
                                                  xq, xk, xv, wtq, wtk, wtv);
  proj_gemm<<<dim3(8, 32, 3), 256, 0, stream>>>(xq, xk, xv, wtq, wtk, wtv, pq, pk, pv);
  vtrans<<<dim3(16, 64), 256, 0, stream>>>(pv, vt);
  attn_fused<<<dim3(512), 512, 0, stream>>>(pq, pk, vt, out);
}

// Round 23
// 157.904 us; speedup vs baseline: 1.1412x; 1.0342x over previous
//
#include <hip/hip_runtime.h>

typedef short short8 __attribute__((ext_vector_type(8)));
typedef short short4_ __attribute__((ext_vector_type(4)));
typedef float f32x4 __attribute__((ext_vector_type(4)));

#define GLD16(gsrc, ldst) \
  __builtin_amdgcn_global_load_lds((__attribute__((address_space(1))) const void*)(gsrc), \
                                   (__attribute__((address_space(3))) void*)(ldst), 16, 0, 0)

// Raw barrier: wait only for LDS ops (dbuf handoff); global stores stay in flight.
#define BAR() do { asm volatile("s_waitcnt lgkmcnt(0)" ::: "memory"); \
  __builtin_amdgcn_sched_barrier(0); __builtin_amdgcn_s_barrier(); } while (0)

static __device__ __forceinline__ short f2bf(float f) {
  union { float f; unsigned u; } x; x.f = f;
  unsigned r = x.u + 0x7fffu + ((x.u >> 16) & 1u);
  return (short)(r >> 16);
}
static __device__ __forceinline__ float bf2f(unsigned short h) {
  union { unsigned u; float f; } x; x.u = ((unsigned)h) << 16;
  return x.f;
}

// ---------------- kernel 1: cast q,k,v f32 -> bf16  AND pack weights (merged) ----------------
__global__ __launch_bounds__(256) void cast_pack(
    const float* __restrict__ q, const float* __restrict__ k, const float* __restrict__ v,
    const float* __restrict__ wq, const float* __restrict__ wk, const float* __restrict__ wv,
    short* __restrict__ xq, short* __restrict__ xk, short* __restrict__ xv,
    short* __restrict__ oq, short* __restrict__ ok, short* __restrict__ ov) {
  int z = blockIdx.z;
  if (blockIdx.x < 4096) {             // cast q/k/v
    const float* s = (z == 0) ? q : (z == 1) ? k : v;
    short* d = (z == 0) ? xq : (z == 1) ? xk : xv;
    int i = (blockIdx.x * 256 + threadIdx.x) * 4;
    float4 f = *(const float4*)(s + i);
    short4_ o;
    o[0] = f2bf(f.x); o[1] = f2bf(f.y); o[2] = f2bf(f.z); o[3] = f2bf(f.w);
    *(short4_*)(d + i) = o;
  } else {                             // pack W (H,D,DK) -> Bt (H*DK, D)
    const float* W = (z == 0) ? wq : (z == 1) ? wk : wv;
    int c = blockIdx.x - 4096;
    short* o = ((z == 0) ? oq : (z == 1) ? ok : ov) + (size_t)c * 1024;
    int h = c >> 6, kk = c & 63;
    const float* src = W + (size_t)h * 65536 + kk;  // + d*64
    #pragma unroll
    for (int it = 0; it < 4; ++it) {
      int d = it * 256 + threadIdx.x;
      o[d] = f2bf(src[(size_t)d * 64]);
    }
  }
}

// ------------- kernel 2: projection GEMM, BK=64 as two half-tiles (validated) -------------
__global__ __launch_bounds__(256) void proj_gemm(
    const short* __restrict__ xq, const short* __restrict__ xk, const short* __restrict__ xv,
    const short* __restrict__ wq, const short* __restrict__ wk, const short* __restrict__ wv,
    short* __restrict__ pq, short* __restrict__ pk, short* __restrict__ pv) {
  int z = blockIdx.z;
  const short* A  = (z == 0) ? xq : (z == 1) ? xk : xv;
  const short* Bt = (z == 0) ? wq : (z == 1) ? wk : wv;
  short* C        = (z == 0) ? pq : (z == 1) ? pk : pv;
  __shared__ __attribute__((aligned(16))) short As[2][128 * 32];
  __shared__ __attribute__((aligned(16))) short Bs[2][128 * 32];
  int t = threadIdx.x, l = t & 63, w = t >> 6;
  int wr = w >> 1, wc = w & 1;
  int lr = l & 15, lk = l >> 4;
  int bm0 = blockIdx.y * 128, bn0 = blockIdx.x * 128;
  const f32x4 Z = {0.f, 0.f, 0.f, 0.f};
  f32x4 acc[4][4];
  #pragma unroll
  for (int m = 0; m < 4; ++m)
    #pragma unroll
    for (int n = 0; n < 4; ++n) acc[m][n] = Z;

  int boff0 = w * 2 * 1024 + l * 16;
  int row0 = boff0 >> 6, ke0 = (boff0 & 63) >> 1;
  int boff1 = boff0 + 1024;
  int row1 = boff1 >> 6, ke1 = (boff1 & 63) >> 1;
  const short* ga0 = A + (size_t)(bm0 + row0) * 1024 + ke0;
  const short* ga1 = A + (size_t)(bm0 + row1) * 1024 + ke1;
  const short* gb0 = Bt + (size_t)(bn0 + row0) * 1024 + ke0;
  const short* gb1 = Bt + (size_t)(bn0 + row1) * 1024 + ke1;
  int lo = (w * 2) * 512, lo1 = (w * 2 + 1) * 512;

  for (int kb = 0; kb < 1024; kb += 64) {
    #pragma unroll
    for (int hh = 0; hh < 2; ++hh) {
      int kc = kb + hh * 32;
      GLD16(ga0 + kc, As[hh] + lo);
      GLD16(ga1 + kc, As[hh] + lo1);
      GLD16(gb0 + kc, Bs[hh] + lo);
      GLD16(gb1 + kc, Bs[hh] + lo1);
    }
    __syncthreads();
    #pragma unroll
    for (int hh = 0; hh < 2; ++hh) {
      short8 a[4], bfr[4];
      #pragma unroll
      for (int m = 0; m < 4; ++m)
        a[m] = *(const short8*)(As[hh] + (wr * 64 + m * 16 + lr) * 32 + lk * 8);
      #pragma unroll
      for (int n = 0; n < 4; ++n)
        bfr[n] = *(const short8*)(Bs[hh] + (wc * 64 + n * 16 + lr) * 32 + lk * 8);
      __builtin_amdgcn_s_setprio(1);
      #pragma unroll
      for (int m = 0; m < 4; ++m)
        #pragma unroll
        for (int n = 0; n < 4; ++n)
          acc[m][n] = __builtin_amdgcn_mfma_f32_16x16x32_bf16(a[m], bfr[n], acc[m][n], 0, 0, 0);
      __builtin_amdgcn_s_setprio(0);
    }
    __syncthreads();
  }
  #pragma unroll
  for (int m = 0; m < 4; ++m)
    #pragma unroll
    for (int n = 0; n < 4; ++n)
      #pragma unroll
      for (int i = 0; i < 4; ++i) {
        int r = bm0 + wr * 64 + m * 16 + lk * 4 + i;
        int cc = bn0 + wc * 64 + n * 16 + lr;
        C[(size_t)r * 1024 + cc] = f2bf(acc[m][n][i]);
      }
}

// ------------- kernel 3: V transpose  pv[b*N+n][h*64+dv] -> vt[hb][dv][n] -------------
__global__ __launch_bounds__(256) void vtrans(
    const short* __restrict__ pv, short* __restrict__ vt) {
  __shared__ short T[64 * 72];
  int t = threadIdx.x;
  int hb = blockIdx.y, h = hb >> 2, b = hb & 3;
  int n0 = blockIdx.x * 64;
  const short* src = pv + (size_t)b * 1048576 + (size_t)n0 * 1024 + h * 64;
  #pragma unroll
  for (int it = 0; it < 2; ++it) {
    int id = it * 256 + t;
    int row = id >> 3, seg = id & 7;
    *(short8*)(T + row * 72 + seg * 8) = *(const short8*)(src + (size_t)row * 1024 + seg * 8);
  }
  __syncthreads();
  short* dst = vt + (size_t)hb * 65536 + n0;
  #pragma unroll
  for (int it = 0; it < 2; ++it) {
    int id = it * 256 + t;
    int dv = id >> 3, seg = id & 7;
    short8 vv;
    #pragma unroll
    for (int jj = 0; jj < 8; ++jj) vv[jj] = T[(seg * 8 + jj) * 72 + dv];
    *(short8*)(dst + (size_t)dv * 1024 + seg * 8) = vv;
  }
}

// ------------- kernel 4: fused attention, SWAPPED QK^T (exact R17 = best 155.8) -------------
__global__ __launch_bounds__(512) void attn_fused(
    const short* __restrict__ pq, const short* __restrict__ pk, const short* __restrict__ vt,
    float* __restrict__ dout) {
  __shared__ __attribute__((aligned(16))) short Ks[2][64 * 64];
  __shared__ __attribute__((aligned(16))) short Vs[2][64 * 64];
  __shared__ __attribute__((aligned(16))) short Ps[128 * 64];
  int t = threadIdx.x, l = t & 63, w = t >> 6;
  int lr = l & 15, lk = l >> 4;
  int r7 = lr & 7;
  int bid = blockIdx.x;
  int swz = (bid & 7) * 64 + (bid >> 3);           // XCD c -> hb in [c*8, c*8+8)
  int hb = swz >> 3, qt = swz & 7;
  int h = hb >> 2, b = hb & 3;                     // hb = h*B + b
  int q0 = qt * 128;
  const short* Qg = pq + (size_t)b * 1048576 + h * 64;
  const short* Kg = pk + (size_t)b * 1048576 + h * 64;
  const short* Vt = vt + (size_t)hb * 65536;
  float* attnp = dout + 4194304 + (size_t)hb * 1048576;
  const f32x4 Z = {0.f, 0.f, 0.f, 0.f};
  const float scale = 0.125f;
  int r0 = w * 16;
  int sj = t >> 3, slt = t & 7;                    // staging: row sj, slot slt
  int stoff = sj * 64 + ((slt ^ (sj & 7)) << 3);   // swizzled staging addr (shorts)

  // Q fragments direct from global (one-time)
  const short* qrow = Qg + (size_t)(q0 + r0 + lr) * 1024;
  short8 aq[2];
  aq[0] = *(const short8*)(qrow + lk * 8);
  aq[1] = *(const short8*)(qrow + 32 + lk * 8);

  short8 ka, va;
  // prologue: stage K chunk 0 -> buf 0
  ka = *(const short8*)(Kg + (size_t)sj * 1024 + slt * 8);
  *(short8*)(Ks[0] + stoff) = ka;
  BAR();

  float s = 0.0f;

  // ---- pass 1: sum of exp(scores); swapped mfma(K, Q) ----
  for (int nc = 0; nc < 16; ++nc) {
    int cur = nc & 1;
    if (nc < 15)
      ka = *(const short8*)(Kg + (size_t)((nc + 1) * 64 + sj) * 1024 + slt * 8);
    f32x4 acc[4] = {Z, Z, Z, Z};
    __builtin_amdgcn_s_setprio(1);
    #pragma unroll
    for (int kk = 0; kk < 2; ++kk)
      #pragma unroll
      for (int n = 0; n < 4; ++n) {
        short8 bk = *(const short8*)(Ks[cur] + (n * 16 + lr) * 64 + (((kk * 4 + lk) ^ r7) << 3));
        acc[n] = __builtin_amdgcn_mfma_f32_16x16x32_bf16(bk, aq[kk], acc[n], 0, 0, 0);
      }
    __builtin_amdgcn_s_setprio(0);
    #pragma unroll
    for (int n = 0; n < 4; ++n)
      s += __expf(acc[n][0] * scale) + __expf(acc[n][1] * scale) +
           __expf(acc[n][2] * scale) + __expf(acc[n][3] * scale);
    if (nc < 15)
      *(short8*)(Ks[cur ^ 1] + stoff) = ka;
    BAR();
  }
  // reduce across the 4 lk-groups sharing each q-row
  s += __shfl_xor(s, 16, 64);
  s += __shfl_xor(s, 32, 64);
  float inv = 1.0f / s;

  // re-prime buf 0 with chunk 0 (K and V)
  ka = *(const short8*)(Kg + (size_t)sj * 1024 + slt * 8);
  va = *(const short8*)(Vt + (size_t)sj * 1024 + slt * 8);
  *(short8*)(Ks[0] + stoff) = ka;
  *(short8*)(Vs[0] + stoff) = va;
  BAR();

  // ---- pass 2: swapped QK -> exp (lane-local) -> attn store from regs + Ps b64 -> PV ----
  f32x4 acco[4] = {Z, Z, Z, Z};
  float* arow = attnp + (size_t)(q0 + r0 + lr) * 1024 + lk * 4;
  short* psrow = Ps + (r0 + lr) * 64;
  int wsw = (lr & 7) << 1;                         // 8B-granular XOR key
  for (int nc = 0; nc < 16; ++nc) {
    int cur = nc & 1;
    if (nc < 15) {
      ka = *(const short8*)(Kg + (size_t)((nc + 1) * 64 + sj) * 1024 + slt * 8);
      va = *(const short8*)(Vt + (size_t)sj * 1024 + (nc + 1) * 64 + slt * 8);
    }
    f32x4 acc[4] = {Z, Z, Z, Z};
    __builtin_amdgcn_s_setprio(1);
    #pragma unroll
    for (int kk = 0; kk < 2; ++kk)
      #pragma unroll
      for (int n = 0; n < 4; ++n) {
        short8 bk = *(const short8*)(Ks[cur] + (n * 16 + lr) * 64 + (((kk * 4 + lk) ^ r7) << 3));
        acc[n] = __builtin_amdgcn_mfma_f32_16x16x32_bf16(bk, aq[kk], acc[n], 0, 0, 0);
      }
    __builtin_amdgcn_s_setprio(0);
    // normalized P: attn f32 direct from regs; bf16 4-pack -> Ps (b64, swizzled)
    #pragma unroll
    for (int n = 0; n < 4; ++n) {
      float e0 = __expf(acc[n][0] * scale) * inv;
      float e1 = __expf(acc[n][1] * scale) * inv;
      float e2 = __expf(acc[n][2] * scale) * inv;
      float e3 = __expf(acc[n][3] * scale) * inv;
      float4 fo = {e0, e1, e2, e3};
      *(float4*)(arow + nc * 64 + n * 16) = fo;    // col = nc*64 + 16n + 4lk + i
      short4_ p4;
      p4[0] = f2bf(e0); p4[1] = f2bf(e1); p4[2] = f2bf(e2); p4[3] = f2bf(e3);
      *(short4_*)(psrow + (((n * 4 + lk) ^ wsw) << 2)) = p4;
    }
    // PV: ap from Ps (b128, swizzled read matches b64 writes), bv from LDS V
    #pragma unroll
    for (int kk = 0; kk < 2; ++kk) {
      short8 ap = *(const short8*)(psrow + (((kk * 4 + lk) ^ r7) << 3));
      __builtin_amdgcn_s_setprio(1);
      #pragma unroll
      for (int f = 0; f < 4; ++f) {
        short8 bv = *(const short8*)(Vs[cur] + (f * 16 + lr) * 64 + (((kk * 4 + lk) ^ r7) << 3));
        acco[f] = __builtin_amdgcn_mfma_f32_16x16x32_bf16(ap, bv, acco[f], 0, 0, 0);
      }
      __builtin_amdgcn_s_setprio(0);
    }
    if (nc < 15) {
      *(short8*)(Ks[cur ^ 1] + stoff) = ka;
      *(short8*)(Vs[cur ^ 1] + stoff) = va;
    }
    BAR();
  }
  // out[b][n][h*64+dv] (f32); PV C-layout unchanged (col=dv, row=q)
  #pragma unroll
  for (int f = 0; f < 4; ++f)
    #pragma unroll
    for (int i = 0; i < 4; ++i) {
      int row = q0 + r0 + lk * 4 + i;
      int dv = f * 16 + lr;
      dout[(size_t)b * 1048576 + (size_t)row * 1024 + h * 64 + dv] = acco[f][i];
    }
}

extern "C" void kernel_launch(void* const* d_in, const int* in_sizes, int n_in,
                              void* d_out, int out_size, void* d_ws, size_t ws_size,
                              hipStream_t stream) {
  const void* big[3] = {0, 0, 0};
  const void* small[3] = {0, 0, 0};
  int nb = 0, ns = 0;
  for (int i = 0; i < n_in && i < 6; ++i) {
    if (in_sizes[i] == 4194304) { if (nb < 3) big[nb++] = d_in[i]; }
    else                        { if (ns < 3) small[ns++] = d_in[i]; }
  }
  const float *q, *k, *v, *wq, *wk, *wv;
  if (nb == 3 && ns == 3) {
    q = (const float*)big[0]; k = (const float*)big[1]; v = (const float*)big[2];
    wq = (const float*)small[0]; wk = (const float*)small[1]; wv = (const float*)small[2];
  } else {
    q = (const float*)d_in[0]; k = (const float*)d_in[1]; v = (const float*)d_in[2];
    wq = (const float*)d_in[3]; wk = (const float*)d_in[4]; wv = (const float*)d_in[5];
  }
  // workspace layout (shorts): total 32,505,856 shorts = 65 MB (validated size)
  short* W   = (short*)d_ws;
  short* xq  = W;
  short* xk  = W + 4194304;
  short* xv  = W + 8388608;
  short* wtq = W + 12582912;
  short* wtk = W + 13631488;
  short* wtv = W + 14680064;
  short* pq  = W + 15728640;
  short* pk  = W + 19922944;
  short* pv  = W + 24117248;
  short* vt  = W + 28311552;
  float* out = (float*)d_out;

  cast_pack<<<dim3(5120, 1, 3), 256, 0, stream>>>(q, k, v, wq, wk, wv,
                                                  xq, xk, xv, wtq, wtk, wtv);
  proj_gemm<<<dim3(8, 32, 3), 256, 0, stream>>>(xq, xk, xv, wtq, wtk, wtv, pq, pk, pv);
  vtrans<<<dim3(16, 64), 256, 0, stream>>>(pv, vt);
  attn_fused<<<dim3(512), 512, 0, stream>>>(pq, pk, vt, out);
}